// Round 5
// baseline (2165.938 us; speedup 1.0000x reference)
//
#include <hip/hip_runtime.h>

typedef __attribute__((ext_vector_type(8))) _Float16 half8;
typedef __attribute__((ext_vector_type(4))) _Float16 half4;
typedef __attribute__((ext_vector_type(4))) float f32x4;

#define HDIM 768
#define NQKV 2304
#define LNEPS 1e-5f

__device__ __forceinline__ void gload_lds16(const void* g, void* l) {
  __builtin_amdgcn_global_load_lds(
      (const __attribute__((address_space(1))) void*)g,
      (__attribute__((address_space(3))) void*)l, 16, 0, 0);
}

// ---------------- weight convert: fp32 -> fp16, concat QKV ----------------
__global__ __launch_bounds__(256) void convert_kernel(
    const float* __restrict__ Wq, const float* __restrict__ Wk, const float* __restrict__ Wv,
    const float* __restrict__ Wo, const float* __restrict__ bq, const float* __restrict__ bk,
    const float* __restrict__ bv,
    _Float16* __restrict__ Wqkv, _Float16* __restrict__ Woh, float* __restrict__ bqkv)
{
  const long NW = 2304L * 768, NO = 768L * 768;
  long i = (long)blockIdx.x * 256 + threadIdx.x;
  if (i < NW) {
    long o = i / 768;
    float val = (o < 768) ? Wq[i] : (o < 1536) ? Wk[i - 768L * 768] : Wv[i - 1536L * 768];
    Wqkv[i] = (_Float16)val;
  } else if (i < NW + NO) {
    Woh[i - NW] = (_Float16)Wo[i - NW];
  } else if (i < NW + NO + 2304) {
    long j = i - NW - NO;
    bqkv[j] = (j < 768) ? bq[j] : (j < 1536) ? bk[j - 768] : bv[j - 1536];
  }
}

// ---------------- LayerNorm: one wave per row of 768, fp16 out ----------------
__global__ __launch_bounds__(256) void ln_kernel(
    const float* __restrict__ feat, const float* __restrict__ gamma,
    const float* __restrict__ beta, _Float16* __restrict__ xout)
{
  const int w = threadIdx.x >> 6, lane = threadIdx.x & 63;
  const long row = (long)blockIdx.x * 4 + w;
  const float* fr = feat + row * HDIM;
  float4 v[3];
  float s = 0.f, ss = 0.f;
#pragma unroll
  for (int i = 0; i < 3; ++i) {
    v[i] = *(const float4*)&fr[(i * 64 + lane) * 4];
    s  += v[i].x + v[i].y + v[i].z + v[i].w;
    ss += v[i].x * v[i].x + v[i].y * v[i].y + v[i].z * v[i].z + v[i].w * v[i].w;
  }
#pragma unroll
  for (int off = 32; off; off >>= 1) {
    s  += __shfl_xor(s, off);
    ss += __shfl_xor(ss, off);
  }
  const float mu = s * (1.f / 768.f);
  const float var = ss * (1.f / 768.f) - mu * mu;
  const float rs = rsqrtf(var + LNEPS);
#pragma unroll
  for (int i = 0; i < 3; ++i) {
    const int idx = (i * 64 + lane) * 4;
    float4 g4 = *(const float4*)&gamma[idx];
    float4 b4 = *(const float4*)&beta[idx];
    half4 o;
    o[0] = (_Float16)((v[i].x - mu) * rs * g4.x + b4.x);
    o[1] = (_Float16)((v[i].y - mu) * rs * g4.y + b4.y);
    o[2] = (_Float16)((v[i].z - mu) * rs * g4.z + b4.z);
    o[3] = (_Float16)((v[i].w - mu) * rs * g4.w + b4.w);
    *(half4*)&xout[row * HDIM + idx] = o;
  }
}

// ---------------- GEMM: C[M,N] = A[M,K] * W[N,K]^T (+bias, +residual) ----------------
// 256x256 tile, 2 K-tiles(BK=64)/iteration, 8 phases/iteration (T3+T4+T5),
// 8 waves (2M x 4N). LDS layout [buf][cc][row][16B]: conflict-free fragment
// reads (16 lanes same cc, stride 16B -> 2 lanes/bank) AND linear k-half
// staging via global_load_lds (no swizzle needed on either side).
// Staging: 1 k-half unit (4 cc-cols, 2 gload_lds/thread) per phase.
// vmcnt(6) only at phases 4 and 8 (6-phase issue-to-guard distance).
template <int EPI>
__global__ __launch_bounds__(512, 2) void gemm_kernel(
    const _Float16* __restrict__ A, long lda,
    const _Float16* __restrict__ W,
    const float* __restrict__ bias,
    _Float16* __restrict__ Ch,            // EPI==0: fp16 out
    float* __restrict__ Cf,               // EPI==1: fp32 out (+residual)
    const _Float16* __restrict__ xres,
    long ldc, int ntiles)
{
  // element offset: buf*16384 + cc*2048 + row*8   (fp16 units)
  __shared__ _Float16 As[2 * 8 * 2048];
  __shared__ _Float16 Bs[2 * 8 * 2048];

  const int tid = threadIdx.x;
  const int w = tid >> 6, lane = tid & 63;
  const int quad = lane >> 4, l16 = lane & 15;
  const int wm = w >> 2, wn = w & 3;       // 2 x 4 wave grid; wave tile 128x64

  // XCD-chunked swizzle (grid divisible by 8)
  const int nwg = gridDim.x;
  const int orig = blockIdx.x;
  const int bid = (orig & 7) * (nwg >> 3) + (orig >> 3);
  const long mt = bid / ntiles;
  const int  nt = bid % ntiles;
  const long m0 = mt * 256;
  const long n0 = (long)nt * 256;

  // staging mapping: thread covers (cc = h*4 + u*2 + scc, row = srow), u in {0,1}
  const int srow = tid & 255;              // per-lane
  const int scc  = tid >> 8;               // wave-uniform (0 or 1)
  const _Float16* aG = A + (m0 + srow) * lda;
  const _Float16* bG = W + (n0 + srow) * HDIM;
  const int ldsw = (w & 3) * 512;          // wave-uniform LDS base part

#define STAGE_A(buf_, t_, h_)                                                 \
  do { _Pragma("unroll") for (int u_ = 0; u_ < 2; ++u_) {                     \
      const int cc_ = (h_) * 4 + u_ * 2 + scc;                                \
      gload_lds16(aG + (long)(t_) * 64 + cc_ * 8,                             \
                  &As[(buf_) * 16384 + cc_ * 2048 + ldsw]); } } while (0)
#define STAGE_B(buf_, t_, h_)                                                 \
  do { _Pragma("unroll") for (int u_ = 0; u_ < 2; ++u_) {                     \
      const int cc_ = (h_) * 4 + u_ * 2 + scc;                                \
      gload_lds16(bG + (long)(t_) * 64 + cc_ * 8,                             \
                  &Bs[(buf_) * 16384 + cc_ * 2048 + ldsw]); } } while (0)
#define LDA_FRAGS(cb_, kk_, mh_)                                              \
  do { _Pragma("unroll") for (int i_ = 0; i_ < 4; ++i_)                       \
      af[i_] = *(const half8*)&As[(cb_) * 16384 + ((kk_) * 4 + quad) * 2048   \
                + (wm * 128 + ((mh_) * 4 + i_) * 16 + l16) * 8]; } while (0)
#define LDB_FRAGS(cb_, kk_)                                                   \
  do { _Pragma("unroll") for (int i_ = 0; i_ < 4; ++i_)                       \
      bf[i_] = *(const half8*)&Bs[(cb_) * 16384 + ((kk_) * 4 + quad) * 2048   \
                + (wn * 64 + i_ * 16 + l16) * 8]; } while (0)
#define MFMA16(mh_)                                                           \
  do { __builtin_amdgcn_s_setprio(1);                                         \
    _Pragma("unroll") for (int i_ = 0; i_ < 4; ++i_)                          \
      _Pragma("unroll") for (int n_ = 0; n_ < 4; ++n_)                        \
        acc[(mh_) * 4 + i_][n_] = __builtin_amdgcn_mfma_f32_16x16x32_f16(     \
            af[i_], bf[n_], acc[(mh_) * 4 + i_][n_], 0, 0, 0);                \
    __builtin_amdgcn_s_setprio(0); } while (0)
#define BAR() __builtin_amdgcn_s_barrier()
#define LGKM0() do { asm volatile("s_waitcnt lgkmcnt(0)" ::: "memory");       \
                  __builtin_amdgcn_sched_barrier(0); } while (0)
#define VM(n_) asm volatile("s_waitcnt vmcnt(" #n_ ")" ::: "memory")

  f32x4 acc[8][4] = {};
  half8 af[4], bf[4];

  // prologue: T0 (buf0) fully + T1 (buf1) B-kk0, A-kk0, B-kk1. (T1 A-kk1 at it0-P1)
  STAGE_B(0, 0, 0); STAGE_A(0, 0, 0); STAGE_B(0, 0, 1); STAGE_A(0, 0, 1);
  STAGE_B(1, 1, 0); STAGE_A(1, 1, 0); STAGE_B(1, 1, 1);
  VM(6);                                   // T0 fully landed
  BAR();

  for (int it = 0; it < 6; ++it) {
    const int t2 = 2 * it + 2, t3 = 2 * it + 3;
    const bool st = (it < 5);
    // P1: buf0 kk0 lo
    LDA_FRAGS(0, 0, 0); LDB_FRAGS(0, 0);
    STAGE_A(1, 2 * it + 1, 1);
    BAR(); LGKM0(); MFMA16(0); BAR();
    // P2: buf0 kk0 hi
    LDA_FRAGS(0, 0, 1);
    if (st) STAGE_B(0, t2, 0);
    BAR(); LGKM0(); MFMA16(1); BAR();
    // P3: buf0 kk1 lo
    LDA_FRAGS(0, 1, 0); LDB_FRAGS(0, 1);
    if (st) STAGE_A(0, t2, 0);
    BAR(); LGKM0(); MFMA16(0); BAR();
    // P4: buf0 kk1 hi
    LDA_FRAGS(0, 1, 1);
    if (st) { STAGE_B(0, t2, 1); VM(6); } else { VM(4); }
    BAR(); LGKM0(); MFMA16(1); BAR();
    // P5: buf1 kk0 lo
    LDA_FRAGS(1, 0, 0); LDB_FRAGS(1, 0);
    if (st) STAGE_A(0, t2, 1);
    BAR(); LGKM0(); MFMA16(0); BAR();
    // P6: buf1 kk0 hi
    LDA_FRAGS(1, 0, 1);
    if (st) STAGE_B(1, t3, 0); else VM(0);
    BAR(); LGKM0(); MFMA16(1); BAR();
    // P7: buf1 kk1 lo
    LDA_FRAGS(1, 1, 0); LDB_FRAGS(1, 1);
    if (st) STAGE_A(1, t3, 0);
    BAR(); LGKM0(); MFMA16(0); BAR();
    // P8: buf1 kk1 hi
    LDA_FRAGS(1, 1, 1);
    if (st) { STAGE_B(1, t3, 1); VM(6); } else { VM(0); }
    BAR(); LGKM0(); MFMA16(1); BAR();
  }

#undef STAGE_A
#undef STAGE_B
#undef LDA_FRAGS
#undef LDB_FRAGS
#undef MFMA16
#undef BAR
#undef LGKM0
#undef VM

  // epilogue: C/D layout col=lane&15, row=(lane>>4)*4+reg (m89-verified)
#pragma unroll
  for (int mi = 0; mi < 8; ++mi) {
#pragma unroll
    for (int ni = 0; ni < 4; ++ni) {
      const long r0 = m0 + wm * 128 + mi * 16 + quad * 4;
      const long cn = n0 + wn * 64 + ni * 16 + l16;
      const float bv = bias[cn];
#pragma unroll
      for (int j = 0; j < 4; ++j) {
        float v = acc[mi][ni][j] + bv;
        if (EPI == 0) {
          Ch[(r0 + j) * ldc + cn] = (_Float16)v;
        } else {
          v += (float)xres[(r0 + j) * HDIM + cn];
          Cf[(r0 + j) * ldc + cn] = v;
        }
      }
    }
  }
}

// ---------------- attention: one wave per batch (3x3 dual softmax) ----------------
__global__ __launch_bounds__(256) void attn_kernel(_Float16* __restrict__ QKV)
{
  const int w = threadIdx.x >> 6, lane = threadIdx.x & 63;
  const long batch = (long)blockIdx.x * 4 + w;
  _Float16* base = QKV + batch * 3 * NQKV;

  float q[3][12], k[3][12], v[3][12];
#pragma unroll
  for (int t = 0; t < 3; ++t) {
    const _Float16* rowp = base + t * NQKV;
#pragma unroll
    for (int i = 0; i < 3; ++i) {
      half4 hq = *(const half4*)&rowp[i * 256 + lane * 4];
      half4 hk = *(const half4*)&rowp[768 + i * 256 + lane * 4];
      half4 hv = *(const half4*)&rowp[1536 + i * 256 + lane * 4];
#pragma unroll
      for (int j = 0; j < 4; ++j) {
        q[t][i * 4 + j] = (float)hq[j];
        k[t][i * 4 + j] = (float)hk[j];
        v[t][i * 4 + j] = (float)hv[j];
      }
    }
  }

  float sp[3][3], sn[3][3];
#pragma unroll
  for (int qi = 0; qi < 3; ++qi) {
#pragma unroll
    for (int ki = 0; ki < 3; ++ki) {
      float ap = 0.f, an = 0.f;
#pragma unroll
      for (int j = 0; j < 12; ++j) {
        const float a = q[qi][j], b = k[ki][j];
        ap += fmaxf(a, 0.f) * fmaxf(b, 0.f);
        an += fminf(a, 0.f) * fminf(b, 0.f);
      }
#pragma unroll
      for (int off = 32; off; off >>= 1) {
        ap += __shfl_xor(ap, off);
        an += __shfl_xor(an, off);
      }
      sp[qi][ki] = ap;
      sn[qi][ki] = an;
    }
  }

  const float scale = 0.03608439182435161f;  // 768^-0.5
  float coef[3][3];
#pragma unroll
  for (int qi = 0; qi < 3; ++qi) {
    const float p0 = sp[qi][0] * scale, p1 = sp[qi][1] * scale, p2 = sp[qi][2] * scale;
    const float n0 = sn[qi][0] * scale, n1 = sn[qi][1] * scale, n2 = sn[qi][2] * scale;
    const float mp = fmaxf(p0, fmaxf(p1, p2));
    const float mn = fmaxf(n0, fmaxf(n1, n2));
    const float ep0 = __expf(p0 - mp), ep1 = __expf(p1 - mp), ep2 = __expf(p2 - mp);
    const float en0 = __expf(n0 - mn), en1 = __expf(n1 - mn), en2 = __expf(n2 - mn);
    const float rp = 1.f / (ep0 + ep1 + ep2);
    const float rn = 1.f / (en0 + en1 + en2);
    coef[qi][0] = ep0 * rp - en0 * rn;
    coef[qi][1] = ep1 * rp - en1 * rn;
    coef[qi][2] = ep2 * rp - en2 * rn;
  }

#pragma unroll
  for (int t = 0; t < 3; ++t) {
#pragma unroll
    for (int i = 0; i < 3; ++i) {
      half4 o;
#pragma unroll
      for (int j = 0; j < 4; ++j) {
        const float val = coef[t][0] * v[0][i * 4 + j]
                        + coef[t][1] * v[1][i * 4 + j]
                        + coef[t][2] * v[2][i * 4 + j];
        o[j] = (_Float16)val;
      }
      *(half4*)&base[t * NQKV + i * 256 + lane * 4] = o;
    }
  }
}

extern "C" void kernel_launch(void* const* d_in, const int* in_sizes, int n_in,
                              void* d_out, int out_size, void* d_ws, size_t ws_size,
                              hipStream_t stream) {
  (void)in_sizes; (void)n_in; (void)out_size; (void)ws_size;
  const float* feat = (const float*)d_in[0];
  const float* Wq   = (const float*)d_in[1];
  const float* bq   = (const float*)d_in[2];
  const float* Wk   = (const float*)d_in[3];
  const float* bk   = (const float*)d_in[4];
  const float* Wv   = (const float*)d_in[5];
  const float* bv   = (const float*)d_in[6];
  const float* Wo   = (const float*)d_in[7];
  const float* bo   = (const float*)d_in[8];
  const float* ln_g = (const float*)d_in[9];
  const float* ln_b = (const float*)d_in[10];

  char* ws = (char*)d_ws;
  _Float16* xh   = (_Float16*)(ws);
  _Float16* QKV  = (_Float16*)(ws + 301989888L);
  _Float16* Wqkv = (_Float16*)(ws + 1207959552L);
  _Float16* Woh  = (_Float16*)(ws + 1211498496L);
  float*    bqkv = (float*)   (ws + 1212678144L);

  convert_kernel<<<9225, 256, 0, stream>>>(Wq, Wk, Wv, Wo, bq, bk, bv, Wqkv, Woh, bqkv);
  ln_kernel<<<49152, 256, 0, stream>>>(feat, ln_g, ln_b, xh);
  // QKV = x @ Wqkv^T + bqkv : M=196608, N=2304 -> grid 768*9
  gemm_kernel<0><<<6912, 512, 0, stream>>>(xh, 768, Wqkv, bqkv, QKV, nullptr, nullptr, 2304, 9);
  attn_kernel<<<16384, 256, 0, stream>>>(QKV);
  // out = attn_out @ Wo^T + bo + x : A = Q-slot of QKV (lda=2304), N=768 -> grid 768*3
  gemm_kernel<1><<<2304, 512, 0, stream>>>(QKV, 2304, Woh, bo, nullptr, (float*)d_out, xh, 768, 3);
}

// Round 6
// 1419.254 us; speedup vs baseline: 1.5261x; 1.5261x over previous
//
#include <hip/hip_runtime.h>

typedef __attribute__((ext_vector_type(8))) _Float16 half8;
typedef __attribute__((ext_vector_type(4))) _Float16 half4;
typedef __attribute__((ext_vector_type(4))) float f32x4;

#define HDIM 768
#define NQKV 2304
#define LNEPS 1e-5f

__device__ __forceinline__ void gload_lds16(const void* g, void* l) {
  __builtin_amdgcn_global_load_lds(
      (const __attribute__((address_space(1))) void*)g,
      (__attribute__((address_space(3))) void*)l, 16, 0, 0);
}

// ---------------- convert: Wq,Wk -> fp16 QKV slots 0,1; biases ----------------
__global__ __launch_bounds__(256) void convert_kernel(
    const float* __restrict__ Wq, const float* __restrict__ Wk,
    const float* __restrict__ bq, const float* __restrict__ bk,
    _Float16* __restrict__ Wqkv, float* __restrict__ bqkv)
{
  const long NW = 589824;  // 768*768
  long i = (long)blockIdx.x * 256 + threadIdx.x;
  if (i < NW) {
    Wqkv[i] = (_Float16)Wq[i];
  } else if (i < 2 * NW) {
    Wqkv[i] = (_Float16)Wk[i - NW];
  } else if (i < 2 * NW + 1536) {
    long j = i - 2 * NW;
    bqkv[j] = (j < 768) ? bq[j] : bk[j - 768];
  }
}

// ---------------- Wvo = Wo @ Wv (fp32 tiled) -> fp16 V-slot; bvo = Wo @ bv ----
// out = x + bo + P @ (x@Wvo^T + bvo) since rowsum(P)=0 folds V-bias exactly.
__global__ __launch_bounds__(256) void wvo_kernel(
    const float* __restrict__ Wo, const float* __restrict__ Wv,
    const float* __restrict__ bv,
    _Float16* __restrict__ Wvo, float* __restrict__ bvo)
{
  if (blockIdx.x == 144) {   // bvo block: bvo[o] = sum_h Wo[o,h]*bv[h]
    for (int o = threadIdx.x; o < 768; o += 256) {
      float s = 0.f;
      for (int h = 0; h < 768; ++h) s += Wo[o * 768 + h] * bv[h];
      bvo[o] = s;
    }
    return;
  }
  __shared__ float As[64][65];
  __shared__ float Bs[64][65];
  const int bm = blockIdx.x / 12, bn = blockIdx.x % 12;
  const int tid = threadIdx.x;
  const int tr = tid >> 4, tc = tid & 15;   // 16x16 threads, 4x4 outputs each
  float acc[4][4] = {};
  for (int k0 = 0; k0 < 768; k0 += 64) {
    __syncthreads();
#pragma unroll
    for (int i = 0; i < 16; ++i) {
      const int e = i * 256 + tid, r = e >> 6, c = e & 63;
      As[r][c] = Wo[(bm * 64 + r) * 768 + (k0 + c)];
      Bs[r][c] = Wv[(k0 + r) * 768 + (bn * 64 + c)];
    }
    __syncthreads();
#pragma unroll 8
    for (int k = 0; k < 64; ++k) {
      float a[4], b[4];
#pragma unroll
      for (int i = 0; i < 4; ++i) a[i] = As[tr * 4 + i][k];
#pragma unroll
      for (int j = 0; j < 4; ++j) b[j] = Bs[k][tc * 4 + j];
#pragma unroll
      for (int i = 0; i < 4; ++i)
#pragma unroll
        for (int j = 0; j < 4; ++j) acc[i][j] += a[i] * b[j];
    }
  }
#pragma unroll
  for (int i = 0; i < 4; ++i)
#pragma unroll
    for (int j = 0; j < 4; ++j)
      Wvo[(bm * 64 + tr * 4 + i) * 768 + bn * 64 + tc * 4 + j] = (_Float16)acc[i][j];
}

// ---------------- LayerNorm: one wave per row of 768, fp16 out ----------------
__global__ __launch_bounds__(256) void ln_kernel(
    const float* __restrict__ feat, const float* __restrict__ gamma,
    const float* __restrict__ beta, _Float16* __restrict__ xout)
{
  const int w = threadIdx.x >> 6, lane = threadIdx.x & 63;
  const long row = (long)blockIdx.x * 4 + w;
  const float* fr = feat + row * HDIM;
  float4 v[3];
  float s = 0.f, ss = 0.f;
#pragma unroll
  for (int i = 0; i < 3; ++i) {
    v[i] = *(const float4*)&fr[(i * 64 + lane) * 4];
    s  += v[i].x + v[i].y + v[i].z + v[i].w;
    ss += v[i].x * v[i].x + v[i].y * v[i].y + v[i].z * v[i].z + v[i].w * v[i].w;
  }
#pragma unroll
  for (int off = 32; off; off >>= 1) {
    s  += __shfl_xor(s, off);
    ss += __shfl_xor(ss, off);
  }
  const float mu = s * (1.f / 768.f);
  const float var = ss * (1.f / 768.f) - mu * mu;
  const float rs = rsqrtf(var + LNEPS);
#pragma unroll
  for (int i = 0; i < 3; ++i) {
    const int idx = (i * 64 + lane) * 4;
    float4 g4 = *(const float4*)&gamma[idx];
    float4 b4 = *(const float4*)&beta[idx];
    half4 o;
    o[0] = (_Float16)((v[i].x - mu) * rs * g4.x + b4.x);
    o[1] = (_Float16)((v[i].y - mu) * rs * g4.y + b4.y);
    o[2] = (_Float16)((v[i].z - mu) * rs * g4.z + b4.z);
    o[3] = (_Float16)((v[i].w - mu) * rs * g4.w + b4.w);
    *(half4*)&xout[row * HDIM + idx] = o;
  }
}

// ---------------- GEMM (R3-proven): C[M,N] = A[M,K] * W[N,K]^T + bias -------
// 256x256 tile, BK=64, 8 waves (2M x 4N), depth-2 K-tile prefetch with counted
// vmcnt(8), raw s_barrier, zero-conflict XOR swizzle (rule #21).
__global__ __launch_bounds__(512, 2) void gemm_kernel(
    const _Float16* __restrict__ A, long lda,
    const _Float16* __restrict__ W,
    const float* __restrict__ bias,
    _Float16* __restrict__ Ch,
    long ldc, int ntiles)
{
  __shared__ _Float16 As[2][256 * 64];
  __shared__ _Float16 Bs[2][256 * 64];

  const int tid = threadIdx.x;
  const int w = tid >> 6, lane = tid & 63;
  const int quad = lane >> 4, l16 = lane & 15;
  const int wm = w >> 2, wn = w & 3;     // 2 x 4 wave grid; wave tile 128x64

  // XCD-chunked swizzle (grid divisible by 8)
  const int nwg = gridDim.x;
  const int orig = blockIdx.x;
  const int bid = (orig & 7) * (nwg >> 3) + (orig >> 3);

  const long mt = bid / ntiles;
  const int  nt = bid % ntiles;
  const long m0 = mt * 256;
  const long n0 = (long)nt * 256;

  const _Float16* aptr[4];
  const _Float16* bptr[4];
  int ldsoff[4];
#pragma unroll
  for (int i = 0; i < 4; ++i) {
    const int chunk = i * 512 + tid;
    const int r = chunk >> 3;
    const int cc = (chunk & 7) ^ (r & 7);
    aptr[i] = A + (m0 + r) * lda + cc * 8;
    bptr[i] = W + (n0 + r) * HDIM + cc * 8;
    ldsoff[i] = i * 4096 + w * 512;       // fp16 elements, wave-uniform base
  }

  f32x4 acc[8][4] = {};

#define STAGE(buf_, t_)                                            \
  do {                                                             \
    const long k0_ = (long)(t_) * 64;                              \
    _Pragma("unroll")                                              \
    for (int i_ = 0; i_ < 4; ++i_)                                 \
      gload_lds16(aptr[i_] + k0_, &As[(buf_)][ldsoff[i_]]);        \
    _Pragma("unroll")                                              \
    for (int i_ = 0; i_ < 4; ++i_)                                 \
      gload_lds16(bptr[i_] + k0_, &Bs[(buf_)][ldsoff[i_]]);        \
  } while (0)

  STAGE(0, 0);
  STAGE(1, 1);
  asm volatile("s_waitcnt vmcnt(8)" ::: "memory");   // tile 0 landed
  __builtin_amdgcn_s_barrier();
  __builtin_amdgcn_sched_barrier(0);

  for (int t = 0; t < 12; ++t) {
    const int buf = t & 1;
    const _Float16* as = &As[buf][0];
    const _Float16* bs = &Bs[buf][0];
#pragma unroll
    for (int kk = 0; kk < 2; ++kk) {
      half8 af[8], bf[4];
#pragma unroll
      for (int mi = 0; mi < 8; ++mi) {
        const int r = wm * 128 + mi * 16 + l16;
        const int cc = kk * 4 + quad;
        af[mi] = *(const half8*)&as[r * 64 + ((cc ^ (r & 7)) * 8)];
      }
#pragma unroll
      for (int ni = 0; ni < 4; ++ni) {
        const int r = wn * 64 + ni * 16 + l16;
        const int cc = kk * 4 + quad;
        bf[ni] = *(const half8*)&bs[r * 64 + ((cc ^ (r & 7)) * 8)];
      }
      __builtin_amdgcn_s_setprio(1);
#pragma unroll
      for (int mi = 0; mi < 8; ++mi)
#pragma unroll
        for (int ni = 0; ni < 4; ++ni)
          acc[mi][ni] = __builtin_amdgcn_mfma_f32_16x16x32_f16(af[mi], bf[ni], acc[mi][ni], 0, 0, 0);
      __builtin_amdgcn_s_setprio(0);
    }
    __builtin_amdgcn_sched_barrier(0);
    __builtin_amdgcn_s_barrier();          // all waves done reading buf[t&1]
    __builtin_amdgcn_sched_barrier(0);
    if (t < 10) STAGE(buf, t + 2);         // overwrite just-consumed buffer
    if (t < 11) {
      if (t < 10) asm volatile("s_waitcnt vmcnt(8)" ::: "memory");  // tile t+1 landed
      else        asm volatile("s_waitcnt vmcnt(0)" ::: "memory");  // tail: tile 11
      __builtin_amdgcn_s_barrier();        // tile t+1 visible to all waves
      __builtin_amdgcn_sched_barrier(0);
    }
  }
#undef STAGE

  // epilogue: C/D layout col=lane&15, row=(lane>>4)*4+reg (m89-verified)
#pragma unroll
  for (int mi = 0; mi < 8; ++mi) {
#pragma unroll
    for (int ni = 0; ni < 4; ++ni) {
      const long r0 = m0 + wm * 128 + mi * 16 + quad * 4;
      const long cn = n0 + wn * 64 + ni * 16 + l16;
      const float bv = bias[cn];
#pragma unroll
      for (int j = 0; j < 4; ++j)
        Ch[(r0 + j) * ldc + cn] = (_Float16)(acc[mi][ni][j] + bv);
    }
  }
}

// ---------------- attn_out: P(3x3) then out = xh + bo + P@VO (fp32) ----------
// One wave per batch. QKV = [Q | K | VO'] where VO' = x@Wvo^T + bvo already
// carries the output projection (VO-bias folds bv exactly since rowsum(P)=0).
__global__ __launch_bounds__(256) void attn_out_kernel(
    const _Float16* __restrict__ QKV, const _Float16* __restrict__ xh,
    const float* __restrict__ bo, float* __restrict__ out)
{
  const int w = threadIdx.x >> 6, lane = threadIdx.x & 63;
  const long batch = (long)blockIdx.x * 4 + w;
  const _Float16* base = QKV + batch * 3 * NQKV;

  float q[3][12], k[3][12], vo[3][12];
#pragma unroll
  for (int t = 0; t < 3; ++t) {
    const _Float16* rowp = base + t * NQKV;
#pragma unroll
    for (int i = 0; i < 3; ++i) {
      half4 hq = *(const half4*)&rowp[i * 256 + lane * 4];
      half4 hk = *(const half4*)&rowp[768 + i * 256 + lane * 4];
      half4 hv = *(const half4*)&rowp[1536 + i * 256 + lane * 4];
#pragma unroll
      for (int j = 0; j < 4; ++j) {
        q[t][i * 4 + j]  = (float)hq[j];
        k[t][i * 4 + j]  = (float)hk[j];
        vo[t][i * 4 + j] = (float)hv[j];
      }
    }
  }

  float sp[3][3], sn[3][3];
#pragma unroll
  for (int qi = 0; qi < 3; ++qi) {
#pragma unroll
    for (int ki = 0; ki < 3; ++ki) {
      float ap = 0.f, an = 0.f;
#pragma unroll
      for (int j = 0; j < 12; ++j) {
        const float a = q[qi][j], b = k[ki][j];
        ap += fmaxf(a, 0.f) * fmaxf(b, 0.f);
        an += fminf(a, 0.f) * fminf(b, 0.f);
      }
#pragma unroll
      for (int off = 32; off; off >>= 1) {
        ap += __shfl_xor(ap, off);
        an += __shfl_xor(an, off);
      }
      sp[qi][ki] = ap;
      sn[qi][ki] = an;
    }
  }

  const float scale = 0.03608439182435161f;  // 768^-0.5
  float coef[3][3];
#pragma unroll
  for (int qi = 0; qi < 3; ++qi) {
    const float p0 = sp[qi][0] * scale, p1 = sp[qi][1] * scale, p2 = sp[qi][2] * scale;
    const float n0 = sn[qi][0] * scale, n1 = sn[qi][1] * scale, n2 = sn[qi][2] * scale;
    const float mp = fmaxf(p0, fmaxf(p1, p2));
    const float mn = fmaxf(n0, fmaxf(n1, n2));
    const float ep0 = __expf(p0 - mp), ep1 = __expf(p1 - mp), ep2 = __expf(p2 - mp);
    const float en0 = __expf(n0 - mn), en1 = __expf(n1 - mn), en2 = __expf(n2 - mn);
    const float rp = 1.f / (ep0 + ep1 + ep2);
    const float rn = 1.f / (en0 + en1 + en2);
    coef[qi][0] = ep0 * rp - en0 * rn;
    coef[qi][1] = ep1 * rp - en1 * rn;
    coef[qi][2] = ep2 * rp - en2 * rn;
  }

#pragma unroll
  for (int t = 0; t < 3; ++t) {
    const long row = batch * 3 + t;
#pragma unroll
    for (int i = 0; i < 3; ++i) {
      const int idx = i * 256 + lane * 4;
      half4 hx = *(const half4*)&xh[row * HDIM + idx];
      float4 b4 = *(const float4*)&bo[idx];
      float4 o;
#pragma unroll
      for (int j = 0; j < 4; ++j) {
        float val = (float)hx[j] + ((const float*)&b4)[j]
                  + coef[t][0] * vo[0][i * 4 + j]
                  + coef[t][1] * vo[1][i * 4 + j]
                  + coef[t][2] * vo[2][i * 4 + j];
        ((float*)&o)[j] = val;
      }
      *(float4*)&out[row * HDIM + idx] = o;
    }
  }
}

extern "C" void kernel_launch(void* const* d_in, const int* in_sizes, int n_in,
                              void* d_out, int out_size, void* d_ws, size_t ws_size,
                              hipStream_t stream) {
  (void)in_sizes; (void)n_in; (void)out_size; (void)ws_size;
  const float* feat = (const float*)d_in[0];
  const float* Wq   = (const float*)d_in[1];
  const float* bq   = (const float*)d_in[2];
  const float* Wk   = (const float*)d_in[3];
  const float* bk   = (const float*)d_in[4];
  const float* Wv   = (const float*)d_in[5];
  const float* bv   = (const float*)d_in[6];
  const float* Wo   = (const float*)d_in[7];
  const float* bo   = (const float*)d_in[8];
  const float* ln_g = (const float*)d_in[9];
  const float* ln_b = (const float*)d_in[10];

  char* ws = (char*)d_ws;
  // layout: xh [196608*768] fp16 @ 0          (301,989,888)
  //         QKV [196608*2304] fp16 @ 301989888 (905,969,664)
  //         Wqkv [2304*768] fp16  @ 1207959552 (3,538,944)
  //         bqkv [2304] fp32      @ 1211498496 (bvo = bqkv+1536)
  _Float16* xh   = (_Float16*)(ws);
  _Float16* QKV  = (_Float16*)(ws + 301989888L);
  _Float16* Wqkv = (_Float16*)(ws + 1207959552L);
  float*    bqkv = (float*)   (ws + 1211498496L);

  convert_kernel<<<4614, 256, 0, stream>>>(Wq, Wk, bq, bk, Wqkv, bqkv);
  wvo_kernel<<<145, 256, 0, stream>>>(Wo, Wv, bv, Wqkv + 1536L * 768, bqkv + 1536);
  ln_kernel<<<49152, 256, 0, stream>>>(feat, ln_g, ln_b, xh);
  // QKV' = x @ [Wq;Wk;Wvo]^T + [bq;bk;bvo] : M=196608, N=2304 -> grid 768*9
  gemm_kernel<<<6912, 512, 0, stream>>>(xh, 768, Wqkv, bqkv, QKV, 2304, 9);
  attn_out_kernel<<<16384, 256, 0, stream>>>(QKV, xh, bo, (float*)d_out);
}